// Round 2
// baseline (336.566 us; speedup 1.0000x reference)
//
#include <hip/hip_runtime.h>

#define L 4800
#define S 4800
#define C 256
#define NB 2          // batch
#define STRIPS 600    // L/8
#define THRV 0.2f

typedef _Float16 f16;
typedef _Float16 f16x8 __attribute__((ext_vector_type(8)));
typedef float f32x4 __attribute__((ext_vector_type(4)));

// ---------------- K0: f32 -> f16 feature conversion ----------------
__global__ __launch_bounds__(256) void k_convert(const float* __restrict__ a, const float* __restrict__ b,
                                                 f16* __restrict__ ah, f16* __restrict__ bh) {
    const int PER = NB * L * C / 4;  // 614400 float4 chunks per array
    int idx = blockIdx.x * 256 + threadIdx.x;
    const float4* src;
    unsigned long long* dst;  // 4 f16 = 8B
    int i;
    if (idx < PER) { src = reinterpret_cast<const float4*>(a); dst = reinterpret_cast<unsigned long long*>(ah); i = idx; }
    else           { src = reinterpret_cast<const float4*>(b); dst = reinterpret_cast<unsigned long long*>(bh); i = idx - PER; }
    float4 v = src[i];
    union { f16 h[4]; unsigned long long u; } p;
    p.h[0] = (f16)v.x; p.h[1] = (f16)v.y; p.h[2] = (f16)v.z; p.h[3] = (f16)v.w;
    dst[i] = p.u;
}

// ---------------- K1: sim = (f0 . f1^T) / 25.6, f16 MFMA, 64x64 tiles ----------------
__global__ __launch_bounds__(256) void k_gemm(const f16* __restrict__ f0h, const f16* __restrict__ f1h,
                                              float* __restrict__ sim) {
    __shared__ __align__(16) unsigned char lds[65536];  // A: [0,32768) B: [32768,65536), rows of 512B, XOR-swizzled
    const int bi = blockIdx.x, bj = blockIdx.y, n = blockIdx.z;
    const int tid = threadIdx.x;

    // stage A (64x256 f16 = 32KB) and B: fully contiguous global reads, swizzled LDS writes
    const uint4* gA = reinterpret_cast<const uint4*>(f0h + ((size_t)n * L + (size_t)bi * 64) * C);
    const uint4* gB = reinterpret_cast<const uint4*>(f1h + ((size_t)n * S + (size_t)bj * 64) * C);
#pragma unroll
    for (int q = 0; q < 8; ++q) {
        int chunk = tid + 256 * q;           // 0..2047 (16B chunks)
        int r = chunk >> 5;                  // row 0..63
        int bcol = (chunk & 31) << 4;        // byte col 0..496
        int sw = bcol ^ ((r & 7) << 4);      // T2-style XOR swizzle
        *reinterpret_cast<uint4*>(&lds[r * 512 + sw])         = gA[chunk];
        *reinterpret_cast<uint4*>(&lds[32768 + r * 512 + sw]) = gB[chunk];
    }
    __syncthreads();

    const int lane = tid & 63, wid = tid >> 6;
    const int wr = (wid >> 1) * 32, wc = (wid & 1) * 32;  // wave tile 32x32
    const int frow = lane & 15;
    const int fkByte = (lane >> 4) * 16;     // k-group byte offset (8 f16)

    f32x4 acc[2][2] = {};
#pragma unroll
    for (int ks = 0; ks < 8; ++ks) {
        int kByte = ks * 64 + fkByte;
        f16x8 a[2], b[2];
#pragma unroll
        for (int mi = 0; mi < 2; ++mi) {
            int row = wr + mi * 16 + frow;
            a[mi] = *reinterpret_cast<const f16x8*>(&lds[row * 512 + (kByte ^ ((row & 7) << 4))]);
        }
#pragma unroll
        for (int ni = 0; ni < 2; ++ni) {
            int row = wc + ni * 16 + frow;
            b[ni] = *reinterpret_cast<const f16x8*>(&lds[32768 + row * 512 + (kByte ^ ((row & 7) << 4))]);
        }
#pragma unroll
        for (int mi = 0; mi < 2; ++mi)
#pragma unroll
            for (int ni = 0; ni < 2; ++ni)
                acc[mi][ni] = __builtin_amdgcn_mfma_f32_16x16x32_f16(a[mi], b[ni], acc[mi][ni], 0, 0, 0);
    }

    // epilogue: C/D layout col=lane&15, row=(lane>>4)*4+reg (verified layout)
    const float scale = 0.0390625f;  // 1/(C^0.5)^2 / TEMP = 1/25.6 exactly
    const int crow0 = (lane >> 4) * 4;
    const int ccol = lane & 15;
#pragma unroll
    for (int mi = 0; mi < 2; ++mi)
#pragma unroll
        for (int ni = 0; ni < 2; ++ni)
#pragma unroll
            for (int reg = 0; reg < 4; ++reg) {
                int r = bi * 64 + wr + mi * 16 + crow0 + reg;
                int c = bj * 64 + wc + ni * 16 + ccol;
                sim[((size_t)n * L + r) * S + c] = acc[mi][ni][reg] * scale;
            }
}

// ---------------- K2: row sums (exact, full-row ownership) + column-sum strip partials ----------------
__global__ __launch_bounds__(256) void k_stats(const float* __restrict__ sim, float* __restrict__ invRowSum,
                                               float* __restrict__ colPart) {
    const int strip = blockIdx.x, n = blockIdx.y, tid = threadIdx.x;
    const int r0 = strip * 8;
    const float4* base = reinterpret_cast<const float4*>(sim + ((size_t)n * L + r0) * S);
    float4* cp = reinterpret_cast<float4*>(colPart + ((size_t)n * STRIPS + strip) * S);
    float rowPart[8] = {0, 0, 0, 0, 0, 0, 0, 0};
    for (int c = tid; c < S / 4; c += 256) {
        float4 cs = {0.f, 0.f, 0.f, 0.f};
#pragma unroll
        for (int r = 0; r < 8; ++r) {
            float4 v = base[(size_t)r * (S / 4) + c];
            float e0 = __expf(v.x), e1 = __expf(v.y), e2 = __expf(v.z), e3 = __expf(v.w);
            cs.x += e0; cs.y += e1; cs.z += e2; cs.w += e3;
            rowPart[r] += (e0 + e1) + (e2 + e3);
        }
        cp[c] = cs;
    }
    __shared__ float red[4][8];
    const int lane = tid & 63, wid = tid >> 6;
#pragma unroll
    for (int r = 0; r < 8; ++r) {
        float v = rowPart[r];
#pragma unroll
        for (int o = 1; o < 64; o <<= 1) v += __shfl_xor(v, o);
        if (lane == 0) red[wid][r] = v;
    }
    __syncthreads();
    if (tid < 8) {
        float s = (red[0][tid] + red[1][tid]) + (red[2][tid] + red[3][tid]);
        invRowSum[(size_t)n * L + r0 + tid] = 1.0f / s;
    }
}

// ---------------- column reduce: 600 strip partials -> 10 -> 1 (sum variant) ----------------
__global__ __launch_bounds__(256) void k_colreduce_a(const float* __restrict__ part, float* __restrict__ part2) {
    int j = blockIdx.x * 256 + threadIdx.x;
    int n = blockIdx.y, z = blockIdx.z;
    if (j >= S) return;
    const float* p = part + ((size_t)n * STRIPS + (size_t)z * 60) * S + j;
    float s0 = 0, s1 = 0, s2 = 0, s3 = 0;
#pragma unroll
    for (int k = 0; k < 60; k += 4) {
        s0 += p[(size_t)(k + 0) * S];
        s1 += p[(size_t)(k + 1) * S];
        s2 += p[(size_t)(k + 2) * S];
        s3 += p[(size_t)(k + 3) * S];
    }
    part2[((size_t)n * 10 + z) * S + j] = (s0 + s1) + (s2 + s3);
}
__global__ __launch_bounds__(256) void k_colreduce_b(const float* __restrict__ part2, float* __restrict__ invColSum) {
    int idx = blockIdx.x * 256 + threadIdx.x;
    if (idx >= NB * S) return;
    int n = idx / S, j = idx % S;
    const float* p = part2 + (size_t)n * 10 * S + j;
    float s = 0;
#pragma unroll
    for (int z = 0; z < 10; ++z) s += p[(size_t)z * S];
    invColSum[idx] = 1.0f / s;
}

// ---------------- K4: conf in-place + row conf (max,argfirst) + col conf max strip partials ----------------
__global__ __launch_bounds__(256) void k_conf(float* __restrict__ sim, const float* __restrict__ invRowSum,
                                              const float* __restrict__ invColSum,
                                              float* __restrict__ rowConfVal, int* __restrict__ rowConfArg,
                                              float* __restrict__ colPart) {
    const int strip = blockIdx.x, n = blockIdx.y, tid = threadIdx.x;
    const int r0 = strip * 8;
    float4* base = reinterpret_cast<float4*>(sim + ((size_t)n * L + r0) * S);
    const float4* ics = reinterpret_cast<const float4*>(invColSum + (size_t)n * S);
    float4* cp = reinterpret_cast<float4*>(colPart + ((size_t)n * STRIPS + strip) * S);
    float irs[8];
#pragma unroll
    for (int r = 0; r < 8; ++r) irs[r] = invRowSum[(size_t)n * L + r0 + r];
    float bestV[8]; int bestJ[8];
#pragma unroll
    for (int r = 0; r < 8; ++r) { bestV[r] = -1.0f; bestJ[r] = 0; }

    for (int c = tid; c < S / 4; c += 256) {
        float4 ic = ics[c];
        float4 cm = {0.f, 0.f, 0.f, 0.f};
#pragma unroll
        for (int r = 0; r < 8; ++r) {
            float4 v = base[(size_t)r * (S / 4) + c];
            float e0 = __expf(v.x), e1 = __expf(v.y), e2 = __expf(v.z), e3 = __expf(v.w);
            float c0 = e0 * e0 * irs[r] * ic.x;
            float c1 = e1 * e1 * irs[r] * ic.y;
            float c2 = e2 * e2 * irs[r] * ic.z;
            float c3 = e3 * e3 * irs[r] * ic.w;
            float4 cf; cf.x = c0; cf.y = c1; cf.z = c2; cf.w = c3;
            base[(size_t)r * (S / 4) + c] = cf;   // overwrite sim with conf (in-place, same element)
            cm.x = fmaxf(cm.x, c0); cm.y = fmaxf(cm.y, c1); cm.z = fmaxf(cm.z, c2); cm.w = fmaxf(cm.w, c3);
            if (c0 > bestV[r]) { bestV[r] = c0; bestJ[r] = c * 4 + 0; }
            if (c1 > bestV[r]) { bestV[r] = c1; bestJ[r] = c * 4 + 1; }
            if (c2 > bestV[r]) { bestV[r] = c2; bestJ[r] = c * 4 + 2; }
            if (c3 > bestV[r]) { bestV[r] = c3; bestJ[r] = c * 4 + 3; }
        }
        cp[c] = cm;
    }
    __shared__ float rv[4][8]; __shared__ int rj[4][8];
    const int lane = tid & 63, wid = tid >> 6;
#pragma unroll
    for (int r = 0; r < 8; ++r) {
        float v = bestV[r]; int j = bestJ[r];
#pragma unroll
        for (int o = 1; o < 64; o <<= 1) {
            float ov = __shfl_xor(v, o); int oj = __shfl_xor(j, o);
            if (ov > v || (ov == v && oj < j)) { v = ov; j = oj; }
        }
        if (lane == 0) { rv[wid][r] = v; rj[wid][r] = j; }
    }
    __syncthreads();
    if (tid < 8) {
        float v = rv[0][tid]; int j = rj[0][tid];
#pragma unroll
        for (int w = 1; w < 4; ++w) {
            float ov = rv[w][tid]; int oj = rj[w][tid];
            if (ov > v || (ov == v && oj < j)) { v = ov; j = oj; }
        }
        rowConfVal[(size_t)n * L + r0 + tid] = v;
        rowConfArg[(size_t)n * L + r0 + tid] = j;
    }
}

// ---------------- column reduce (max variant) ----------------
__global__ __launch_bounds__(256) void k_colmax_a(const float* __restrict__ part, float* __restrict__ part2) {
    int j = blockIdx.x * 256 + threadIdx.x;
    int n = blockIdx.y, z = blockIdx.z;
    if (j >= S) return;
    const float* p = part + ((size_t)n * STRIPS + (size_t)z * 60) * S + j;
    float m0 = 0, m1 = 0, m2 = 0, m3 = 0;  // conf > 0 always
#pragma unroll
    for (int k = 0; k < 60; k += 4) {
        m0 = fmaxf(m0, p[(size_t)(k + 0) * S]);
        m1 = fmaxf(m1, p[(size_t)(k + 1) * S]);
        m2 = fmaxf(m2, p[(size_t)(k + 2) * S]);
        m3 = fmaxf(m3, p[(size_t)(k + 3) * S]);
    }
    part2[((size_t)n * 10 + z) * S + j] = fmaxf(fmaxf(m0, m1), fmaxf(m2, m3));
}
__global__ __launch_bounds__(256) void k_colmax_b(const float* __restrict__ part2, float* __restrict__ colConfMax) {
    int idx = blockIdx.x * 256 + threadIdx.x;
    if (idx >= NB * S) return;
    int n = idx / S, j = idx % S;
    const float* p = part2 + (size_t)n * 10 * S + j;
    float m = 0;
#pragma unroll
    for (int z = 0; z < 10; ++z) m = fmaxf(m, p[(size_t)z * S]);
    colConfMax[idx] = m;
}

// ---------------- K5: threshold + border + mutual-NN extraction ----------------
__global__ __launch_bounds__(256) void k_final(const float* __restrict__ rowConfVal, const int* __restrict__ rowConfArg,
                                               const float* __restrict__ colConfMax,
                                               float* __restrict__ out_maskv, float* __restrict__ out_jids,
                                               float* __restrict__ out_mconf) {
    int idx = blockIdx.x * 256 + threadIdx.x;
    if (idx >= NB * L) return;
    int n = idx / L, i = idx % L;
    float v = rowConfVal[idx];
    int j = rowConfArg[idx];
    int h0 = i / 80, w0 = i % 80;
    int h1 = j / 80, w1 = j % 80;
    bool ok = (v > THRV)
              && (h0 >= 2) && (h0 < 58) && (w0 >= 2) && (w0 < 78)
              && (h1 >= 2) && (h1 < 58) && (w1 >= 2) && (w1 < 78)
              && (v == colConfMax[(size_t)n * S + j]);
    out_maskv[idx] = ok ? 1.0f : 0.0f;
    out_jids[idx]  = ok ? (float)j : 0.0f;
    out_mconf[idx] = ok ? v : 0.0f;
}

extern "C" void kernel_launch(void* const* d_in, const int* in_sizes, int n_in,
                              void* d_out, int out_size, void* d_ws, size_t ws_size,
                              hipStream_t stream) {
    const float* f0 = (const float*)d_in[0];
    const float* f1 = (const float*)d_in[1];
    float* out = (float*)d_out;
    char* ws = (char*)d_ws;

    // ws layout (bytes, 16B aligned), ~33.5 MB total
    f16*   f0h        = (f16*)(ws + 0);           // 4,915,200
    f16*   f1h        = (f16*)(ws + 4915200);     // 4,915,200
    float* colPart    = (float*)(ws + 9830400);   // 23,040,000 (reused: col sums, then col conf max)
    float* part2      = (float*)(ws + 32870400);  //    384,000
    float* invColSum  = (float*)(ws + 33254400);  //     38,400
    float* invRowSum  = (float*)(ws + 33292800);  //     38,400
    float* rowConfVal = (float*)(ws + 33331200);  //     38,400
    int*   rowConfArg = (int*)  (ws + 33369600);  //     38,400
    float* colConfMax = (float*)(ws + 33408000);  //     38,400

    float* sim = out;  // sim stored in-place in d_out conf region, overwritten by conf
    float* out_maskv = out + (size_t)NB * L * S;
    float* out_jids  = out_maskv + NB * L;
    float* out_mconf = out_jids + NB * L;

    k_convert<<<4800, 256, 0, stream>>>(f0, f1, f0h, f1h);
    k_gemm<<<dim3(75, 75, NB), 256, 0, stream>>>(f0h, f1h, sim);
    k_stats<<<dim3(STRIPS, NB), 256, 0, stream>>>(sim, invRowSum, colPart);
    k_colreduce_a<<<dim3(19, NB, 10), 256, 0, stream>>>(colPart, part2);
    k_colreduce_b<<<(NB * S + 255) / 256, 256, 0, stream>>>(part2, invColSum);
    k_conf<<<dim3(STRIPS, NB), 256, 0, stream>>>(sim, invRowSum, invColSum, rowConfVal, rowConfArg, colPart);
    k_colmax_a<<<dim3(19, NB, 10), 256, 0, stream>>>(colPart, part2);
    k_colmax_b<<<(NB * S + 255) / 256, 256, 0, stream>>>(part2, colConfMax);
    k_final<<<(NB * L + 255) / 256, 256, 0, stream>>>(rowConfVal, rowConfArg, colConfMax,
                                                      out_maskv, out_jids, out_mconf);
}

// Round 6
// 305.151 us; speedup vs baseline: 1.1029x; 1.1029x over previous
//
#include <hip/hip_runtime.h>

#define L 4800
#define S 4800
#define C 256
#define NB 2
#define THRV 0.2f
#define SCALE 0.0390625f   // 1/(sqrt(C))^2 / TEMP = 1/25.6
#define NSTRIP 150         // L/32 row strips
#define NCC 3              // column chunks of 1600
#define CCW 1600
#define NT 64              // cols per tile
#define NTILES 25          // CCW/NT

typedef _Float16 f16;
typedef _Float16 f16x8 __attribute__((ext_vector_type(8)));
typedef float f32x4 __attribute__((ext_vector_type(4)));

typedef __attribute__((address_space(1))) const unsigned int g_as1;
typedef __attribute__((address_space(3))) unsigned int lds_as3;

__device__ __forceinline__ void gload_lds16(const void* g, void* l) {
    __builtin_amdgcn_global_load_lds((g_as1*)g, (lds_as3*)l, 16, 0, 0);
}

// ---------------- K0: f32 -> f16 feature conversion ----------------
__global__ __launch_bounds__(256) void k_convert(const float* __restrict__ a, const float* __restrict__ b,
                                                 f16* __restrict__ ah, f16* __restrict__ bh) {
    const int PER = NB * L * C / 4;
    int idx = blockIdx.x * 256 + threadIdx.x;
    const float4* src;
    unsigned long long* dst;
    int i;
    if (idx < PER) { src = reinterpret_cast<const float4*>(a); dst = reinterpret_cast<unsigned long long*>(ah); i = idx; }
    else           { src = reinterpret_cast<const float4*>(b); dst = reinterpret_cast<unsigned long long*>(bh); i = idx - PER; }
    float4 v = src[i];
    union { f16 h[4]; unsigned long long u; } p;
    p.h[0] = (f16)v.x; p.h[1] = (f16)v.y; p.h[2] = (f16)v.z; p.h[3] = (f16)v.w;
    dst[i] = p.u;
}

// ===================== PASS 1: GEMM + exp + row-sum / col-sum partials =====================
// grid (NSTRIP, NCC, NB), 256 thr. Block: 32 rows x 1600 cols, K=256.
// LDS: B dbuf 2x32KB + A 16KB (A region reused as reduce scratch).
__global__ __launch_bounds__(256) void k_pass1(const f16* __restrict__ f0h, const f16* __restrict__ f1h,
                                               float* __restrict__ rowSumPart, float* __restrict__ colPart) {
    __shared__ __align__(16) unsigned char lds[81920];
    const int strip = blockIdx.x, cc = blockIdx.y, n = blockIdx.z;
    const int tid = threadIdx.x, lane = tid & 63, w = tid >> 6;
    const int fr = lane & 15, kg = lane >> 4;
    const int jbase = cc * CCW;

    // stage A (32 rows x 512B), XOR-swizzled dest
    {
        const uint4* gA = reinterpret_cast<const uint4*>(f0h + ((size_t)n * L + strip * 32) * C);
        uint4* As = reinterpret_cast<uint4*>(lds + 65536);
#pragma unroll
        for (int q = 0; q < 4; ++q) {
            int c = tid + 256 * q;
            int r = c >> 5, bcol = c & 31;
            As[r * 32 + (bcol ^ (r & 7))] = gA[c];
        }
    }
    // stage B tile 0 into buf0 (pre-swizzled source, linear dest)
    const f16* gBbase = f1h + ((size_t)n * S + jbase) * C;
    {
        const uint4* gBt = reinterpret_cast<const uint4*>(gBbase);
#pragma unroll
        for (int i = 0; i < 8; ++i) {
            int q = (w * 8 + i) * 64 + lane;
            int r = q >> 5, bcol = q & 31;
            gload_lds16(gBt + r * 32 + (bcol ^ (r & 7)), lds + (w * 8 + i) * 1024);
        }
    }
    asm volatile("s_waitcnt vmcnt(0)" ::: "memory");
    __syncthreads();

    // A fragments -> registers (all waves hold all 32 rows)
    f16x8 a[2][8];
#pragma unroll
    for (int mi = 0; mi < 2; ++mi)
#pragma unroll
        for (int ks = 0; ks < 8; ++ks) {
            int row = mi * 16 + fr;
            a[mi][ks] = *reinterpret_cast<const f16x8*>(lds + 65536 + (row * 32 + ((ks * 4 + kg) ^ (row & 7))) * 16);
        }

    float rowAcc[8] = {0,0,0,0,0,0,0,0};
    const int rowb = w * 16 + fr;

    for (int t = 0; t < NTILES; ++t) {
        const int cur = t & 1;
        if (t < NTILES - 1) {
            const uint4* gBt = reinterpret_cast<const uint4*>(gBbase + (size_t)(t + 1) * NT * C);
            unsigned char* dst = lds + (cur ^ 1) * 32768;
#pragma unroll
            for (int i = 0; i < 8; ++i) {
                int q = (w * 8 + i) * 64 + lane;
                int r = q >> 5, bcol = q & 31;
                gload_lds16(gBt + r * 32 + (bcol ^ (r & 7)), dst + (w * 8 + i) * 1024);
            }
            asm volatile("s_waitcnt vmcnt(8)" ::: "memory");
        } else {
            asm volatile("s_waitcnt vmcnt(0)" ::: "memory");
        }
        __builtin_amdgcn_s_barrier();
        asm volatile("" ::: "memory");

        const unsigned char* Bb = lds + cur * 32768;
        f32x4 acc0 = {0.f,0.f,0.f,0.f}, acc1 = {0.f,0.f,0.f,0.f};
#pragma unroll
        for (int ks = 0; ks < 8; ++ks) {
            f16x8 bf = *reinterpret_cast<const f16x8*>(Bb + (rowb * 32 + ((ks * 4 + kg) ^ (rowb & 7))) * 16);
            acc0 = __builtin_amdgcn_mfma_f32_16x16x32_f16(a[0][ks], bf, acc0, 0, 0, 0);
            acc1 = __builtin_amdgcn_mfma_f32_16x16x32_f16(a[1][ks], bf, acc1, 0, 0, 0);
        }
        float colv = 0.f;
#pragma unroll
        for (int r4 = 0; r4 < 4; ++r4) {
            float e0 = __expf(acc0[r4] * SCALE); rowAcc[r4] += e0;
            float e1 = __expf(acc1[r4] * SCALE); rowAcc[4 + r4] += e1;
            colv += e0 + e1;
        }
        colv += __shfl_xor(colv, 16); colv += __shfl_xor(colv, 32);
        if (lane < 16)
            colPart[((size_t)n * NSTRIP + strip) * S + jbase + t * NT + w * 16 + lane] = colv;
        asm volatile("" ::: "memory");
        __builtin_amdgcn_s_barrier();
    }

    // row-sum reduce: 16 lanes share each row set
#pragma unroll
    for (int o = 1; o < 16; o <<= 1)
#pragma unroll
        for (int r8 = 0; r8 < 8; ++r8) rowAcc[r8] += __shfl_xor(rowAcc[r8], o);
    float* scratch = reinterpret_cast<float*>(lds + 65536);
    if ((lane & 15) == 0) {
#pragma unroll
        for (int r8 = 0; r8 < 8; ++r8) {
            int row = (r8 >> 2) * 16 + kg * 4 + (r8 & 3);
            scratch[w * 32 + row] = rowAcc[r8];
        }
    }
    __syncthreads();
    if (tid < 32)
        rowSumPart[((size_t)n * NCC + cc) * L + strip * 32 + tid] =
            (scratch[tid] + scratch[32 + tid]) + (scratch[64 + tid] + scratch[96 + tid]);
}

// ---------------- row-sum combine -> invRowSum ----------------
__global__ __launch_bounds__(256) void k_rowinv(const float* __restrict__ rowSumPart, float* __restrict__ invRowSum) {
    int idx = blockIdx.x * 256 + threadIdx.x;
    if (idx >= NB * L) return;
    int n = idx / L, row = idx % L;
    float s = rowSumPart[((size_t)n * NCC + 0) * L + row]
            + rowSumPart[((size_t)n * NCC + 1) * L + row]
            + rowSumPart[((size_t)n * NCC + 2) * L + row];
    invRowSum[idx] = 1.0f / s;
}

// ---------------- column reduce: 150 strip partials -> 10 -> 1 (sum) ----------------
__global__ __launch_bounds__(256) void k_colreduce_a(const float* __restrict__ part, float* __restrict__ part2) {
    int j = blockIdx.x * 256 + threadIdx.x;
    int n = blockIdx.y, z = blockIdx.z;
    if (j >= S) return;
    const float* p = part + ((size_t)n * NSTRIP + (size_t)z * 15) * S + j;
    float s = 0.f;
#pragma unroll
    for (int k = 0; k < 15; ++k) s += p[(size_t)k * S];
    part2[((size_t)n * 10 + z) * S + j] = s;
}
__global__ __launch_bounds__(256) void k_colreduce_b(const float* __restrict__ part2, float* __restrict__ invColSum) {
    int idx = blockIdx.x * 256 + threadIdx.x;
    if (idx >= NB * S) return;
    int n = idx / S, j = idx % S;
    const float* p = part2 + (size_t)n * 10 * S + j;
    float s = 0.f;
#pragma unroll
    for (int z = 0; z < 10; ++z) s += p[(size_t)z * S];
    invColSum[idx] = 1.0f / s;
}

// ===================== PASS 2: GEMM + conf write + row argmax + col-max partials =====================
__global__ __launch_bounds__(256) void k_pass2(const f16* __restrict__ f0h, const f16* __restrict__ f1h,
                                               const float* __restrict__ invRowSum, const float* __restrict__ invColSum,
                                               float* __restrict__ conf,
                                               float* __restrict__ rowValPart, int* __restrict__ rowArgPart,
                                               float* __restrict__ colPart) {
    __shared__ __align__(16) unsigned char lds[81920];
    const int strip = blockIdx.x, cc = blockIdx.y, n = blockIdx.z;
    const int tid = threadIdx.x, lane = tid & 63, w = tid >> 6;
    const int fr = lane & 15, kg = lane >> 4;
    const int jbase = cc * CCW;

    {
        const uint4* gA = reinterpret_cast<const uint4*>(f0h + ((size_t)n * L + strip * 32) * C);
        uint4* As = reinterpret_cast<uint4*>(lds + 65536);
#pragma unroll
        for (int q = 0; q < 4; ++q) {
            int c = tid + 256 * q;
            int r = c >> 5, bcol = c & 31;
            As[r * 32 + (bcol ^ (r & 7))] = gA[c];
        }
    }
    const f16* gBbase = f1h + ((size_t)n * S + jbase) * C;
    {
        const uint4* gBt = reinterpret_cast<const uint4*>(gBbase);
#pragma unroll
        for (int i = 0; i < 8; ++i) {
            int q = (w * 8 + i) * 64 + lane;
            int r = q >> 5, bcol = q & 31;
            gload_lds16(gBt + r * 32 + (bcol ^ (r & 7)), lds + (w * 8 + i) * 1024);
        }
    }
    asm volatile("s_waitcnt vmcnt(0)" ::: "memory");
    __syncthreads();

    f16x8 a[2][8];
#pragma unroll
    for (int mi = 0; mi < 2; ++mi)
#pragma unroll
        for (int ks = 0; ks < 8; ++ks) {
            int row = mi * 16 + fr;
            a[mi][ks] = *reinterpret_cast<const f16x8*>(lds + 65536 + (row * 32 + ((ks * 4 + kg) ^ (row & 7))) * 16);
        }

    float irs[8];
#pragma unroll
    for (int r8 = 0; r8 < 8; ++r8)
        irs[r8] = invRowSum[(size_t)n * L + strip * 32 + (r8 >> 2) * 16 + kg * 4 + (r8 & 3)];

    float bestV[8]; int bestJ[8];
#pragma unroll
    for (int r8 = 0; r8 < 8; ++r8) { bestV[r8] = -1.0f; bestJ[r8] = 0; }

    const int rowb = w * 16 + fr;
    float* crowBase = conf + ((size_t)n * L + strip * 32) * S + jbase + w * 16 + fr;

    for (int t = 0; t < NTILES; ++t) {
        const int cur = t & 1;
        if (t < NTILES - 1) {
            const uint4* gBt = reinterpret_cast<const uint4*>(gBbase + (size_t)(t + 1) * NT * C);
            unsigned char* dst = lds + (cur ^ 1) * 32768;
#pragma unroll
            for (int i = 0; i < 8; ++i) {
                int q = (w * 8 + i) * 64 + lane;
                int r = q >> 5, bcol = q & 31;
                gload_lds16(gBt + r * 32 + (bcol ^ (r & 7)), dst + (w * 8 + i) * 1024);
            }
            asm volatile("s_waitcnt vmcnt(8)" ::: "memory");
        } else {
            asm volatile("s_waitcnt vmcnt(0)" ::: "memory");
        }
        __builtin_amdgcn_s_barrier();
        asm volatile("" ::: "memory");

        const unsigned char* Bb = lds + cur * 32768;
        f32x4 acc0 = {0.f,0.f,0.f,0.f}, acc1 = {0.f,0.f,0.f,0.f};
#pragma unroll
        for (int ks = 0; ks < 8; ++ks) {
            f16x8 bf = *reinterpret_cast<const f16x8*>(Bb + (rowb * 32 + ((ks * 4 + kg) ^ (rowb & 7))) * 16);
            acc0 = __builtin_amdgcn_mfma_f32_16x16x32_f16(a[0][ks], bf, acc0, 0, 0, 0);
            acc1 = __builtin_amdgcn_mfma_f32_16x16x32_f16(a[1][ks], bf, acc1, 0, 0, 0);
        }

        const int jcol = jbase + t * NT + w * 16 + fr;
        float icol = invColSum[(size_t)n * S + jcol];
        float* crow = crowBase + t * NT;
        float cmax = 0.f;
#pragma unroll
        for (int r4 = 0; r4 < 4; ++r4) {
            float e0 = __expf(acc0[r4] * SCALE);
            float cf0 = e0 * e0 * irs[r4] * icol;
            crow[(size_t)(kg * 4 + r4) * S] = cf0;
            if (cf0 > bestV[r4]) { bestV[r4] = cf0; bestJ[r4] = jcol; }
            float e1 = __expf(acc1[r4] * SCALE);
            float cf1 = e1 * e1 * irs[4 + r4] * icol;
            crow[(size_t)(16 + kg * 4 + r4) * S] = cf1;
            if (cf1 > bestV[4 + r4]) { bestV[4 + r4] = cf1; bestJ[4 + r4] = jcol; }
            cmax = fmaxf(cmax, fmaxf(cf0, cf1));
        }
        cmax = fmaxf(cmax, __shfl_xor(cmax, 16));
        cmax = fmaxf(cmax, __shfl_xor(cmax, 32));
        if (lane < 16)
            colPart[((size_t)n * NSTRIP + strip) * S + jcol] = cmax;  // lanes 0-15: jcol spans the 16 cols
        asm volatile("" ::: "memory");
        __builtin_amdgcn_s_barrier();
    }

    // row max/argmax reduce across the 16 col-lanes (tie -> min j)
#pragma unroll
    for (int o = 1; o < 16; o <<= 1)
#pragma unroll
        for (int r8 = 0; r8 < 8; ++r8) {
            float ov = __shfl_xor(bestV[r8], o);
            int oj = __shfl_xor(bestJ[r8], o);
            if (ov > bestV[r8] || (ov == bestV[r8] && oj < bestJ[r8])) { bestV[r8] = ov; bestJ[r8] = oj; }
        }
    float* sv = reinterpret_cast<float*>(lds + 65536);
    int* sj = reinterpret_cast<int*>(lds + 65536 + 512);
    if ((lane & 15) == 0) {
#pragma unroll
        for (int r8 = 0; r8 < 8; ++r8) {
            int row = (r8 >> 2) * 16 + kg * 4 + (r8 & 3);
            sv[w * 32 + row] = bestV[r8];
            sj[w * 32 + row] = bestJ[r8];
        }
    }
    __syncthreads();
    if (tid < 32) {
        float v = sv[tid]; int j = sj[tid];
#pragma unroll
        for (int w2 = 1; w2 < 4; ++w2) {
            float ov = sv[w2 * 32 + tid]; int oj = sj[w2 * 32 + tid];
            if (ov > v || (ov == v && oj < j)) { v = ov; j = oj; }
        }
        rowValPart[((size_t)n * NCC + cc) * L + strip * 32 + tid] = v;
        rowArgPart[((size_t)n * NCC + cc) * L + strip * 32 + tid] = j;
    }
}

// ---------------- column reduce (max) ----------------
__global__ __launch_bounds__(256) void k_colmax_a(const float* __restrict__ part, float* __restrict__ part2) {
    int j = blockIdx.x * 256 + threadIdx.x;
    int n = blockIdx.y, z = blockIdx.z;
    if (j >= S) return;
    const float* p = part + ((size_t)n * NSTRIP + (size_t)z * 15) * S + j;
    float m = 0.f;
#pragma unroll
    for (int k = 0; k < 15; ++k) m = fmaxf(m, p[(size_t)k * S]);
    part2[((size_t)n * 10 + z) * S + j] = m;
}
__global__ __launch_bounds__(256) void k_colmax_b(const float* __restrict__ part2, float* __restrict__ colConfMax) {
    int idx = blockIdx.x * 256 + threadIdx.x;
    if (idx >= NB * S) return;
    int n = idx / S, j = idx % S;
    const float* p = part2 + (size_t)n * 10 * S + j;
    float m = 0.f;
#pragma unroll
    for (int z = 0; z < 10; ++z) m = fmaxf(m, p[(size_t)z * S]);
    colConfMax[idx] = m;
}

// ---------------- final: combine row partials + threshold + border + mutual-NN ----------------
__global__ __launch_bounds__(256) void k_final(const float* __restrict__ rowValPart, const int* __restrict__ rowArgPart,
                                               const float* __restrict__ colConfMax,
                                               float* __restrict__ out_maskv, float* __restrict__ out_jids,
                                               float* __restrict__ out_mconf) {
    int idx = blockIdx.x * 256 + threadIdx.x;
    if (idx >= NB * L) return;
    int n = idx / L, i = idx % L;
    float v = rowValPart[((size_t)n * NCC + 0) * L + i];
    int j = rowArgPart[((size_t)n * NCC + 0) * L + i];
#pragma unroll
    for (int cc = 1; cc < NCC; ++cc) {
        float ov = rowValPart[((size_t)n * NCC + cc) * L + i];
        int oj = rowArgPart[((size_t)n * NCC + cc) * L + i];
        if (ov > v || (ov == v && oj < j)) { v = ov; j = oj; }
    }
    int h0 = i / 80, w0 = i % 80;
    int h1 = j / 80, w1 = j % 80;
    bool ok = (v > THRV)
              && (h0 >= 2) && (h0 < 58) && (w0 >= 2) && (w0 < 78)
              && (h1 >= 2) && (h1 < 58) && (w1 >= 2) && (w1 < 78)
              && (v == colConfMax[(size_t)n * S + j]);
    out_maskv[idx] = ok ? 1.0f : 0.0f;
    out_jids[idx]  = ok ? (float)j : 0.0f;
    out_mconf[idx] = ok ? v : 0.0f;
}

extern "C" void kernel_launch(void* const* d_in, const int* in_sizes, int n_in,
                              void* d_out, int out_size, void* d_ws, size_t ws_size,
                              hipStream_t stream) {
    const float* f0 = (const float*)d_in[0];
    const float* f1 = (const float*)d_in[1];
    float* out = (float*)d_out;
    char* ws = (char*)d_ws;

    f16*   f0h        = (f16*)(ws + 0);            // 4,915,200
    f16*   f1h        = (f16*)(ws + 4915200);      // 4,915,200
    float* colPart    = (float*)(ws + 9830400);    // 5,760,000 (reused sum->max)
    float* part2      = (float*)(ws + 15590400);   //   384,000
    float* rowSumPart = (float*)(ws + 15974400);   //   115,200
    float* rowValPart = (float*)(ws + 16089600);   //   115,200
    int*   rowArgPart = (int*)  (ws + 16204800);   //   115,200
    float* invRowSum  = (float*)(ws + 16320000);   //    38,400
    float* invColSum  = (float*)(ws + 16358400);   //    38,400
    float* colConfMax = (float*)(ws + 16396800);   //    38,400

    float* conf = out;
    float* out_maskv = out + (size_t)NB * L * S;
    float* out_jids  = out_maskv + NB * L;
    float* out_mconf = out_jids + NB * L;

    k_convert<<<4800, 256, 0, stream>>>(f0, f1, f0h, f1h);
    k_pass1<<<dim3(NSTRIP, NCC, NB), 256, 0, stream>>>(f0h, f1h, rowSumPart, colPart);
    k_rowinv<<<(NB * L + 255) / 256, 256, 0, stream>>>(rowSumPart, invRowSum);
    k_colreduce_a<<<dim3(19, NB, 10), 256, 0, stream>>>(colPart, part2);
    k_colreduce_b<<<(NB * S + 255) / 256, 256, 0, stream>>>(part2, invColSum);
    k_pass2<<<dim3(NSTRIP, NCC, NB), 256, 0, stream>>>(f0h, f1h, invRowSum, invColSum, conf,
                                                       rowValPart, rowArgPart, colPart);
    k_colmax_a<<<dim3(19, NB, 10), 256, 0, stream>>>(colPart, part2);
    k_colmax_b<<<(NB * S + 255) / 256, 256, 0, stream>>>(part2, colConfMax);
    k_final<<<(NB * L + 255) / 256, 256, 0, stream>>>(rowValPart, rowArgPart, colConfMax,
                                                      out_maskv, out_jids, out_mconf);
}